// Round 3
// baseline (449.075 us; speedup 1.0000x reference)
//
#include <hip/hip_runtime.h>

// OccurrencePool restructured:
//   r1  = relu(W1 x + b1)                          (bf16 MFMA, 34.4 GF)
//   occ = |W3 relu(W2o relu(W1o x + b1o) + b2o)|   (bf16 MFMA, 10.2 GF)
//   M[b,o,j]   = sum_s occ[b,o,s] r1[b,j,s]        (bf16 MFMA, 4.3 GF)
//   out[b,o,c] = (sum_j M[o,j] W2[c,j] + b2[c]*sumocc[b,o]) / S
// R3: single-barrier ping-pong K-loops (glds for k+1 issued right after the
// barrier, overlapping compute of k); sumocc computed in k_occ epilogue;
// k_epi replaced by tiled k_out (w2 read 32 MB total instead of 268 MB).

#define S_TOT 16384  // T*H*W per batch

typedef __attribute__((ext_vector_type(8))) short bf8_t;  // 8 bf16 (4 VGPRs)
typedef __attribute__((ext_vector_type(4))) short s4_t;   // 4 bf16
typedef __attribute__((ext_vector_type(4))) float f4_t;

#define MFMA __builtin_amdgcn_mfma_f32_16x16x32_bf16

__device__ __forceinline__ short f2bf(float f) {
  union { float f; unsigned u; } v; v.f = f;
  unsigned u = v.u + 0x7FFFu + ((v.u >> 16) & 1u);  // RNE
  return (short)(u >> 16);
}

__device__ __forceinline__ void glds16(const void* g, void* l) {
  __builtin_amdgcn_global_load_lds(
      (const __attribute__((address_space(1))) void*)g,
      (__attribute__((address_space(3))) void*)l, 16, 0, 0);
}

// Stage a 128-row x 64-short tile (global row stride 512 shorts) into planar
// LDS: slot = c*128 + r (16B slots), c = k-chunk (0..7), r = row.
__device__ __forceinline__ void stage_tile(const short* gbase, short* lds,
                                           int wv, int lane) {
#pragma unroll
  for (int i = 0; i < 4; ++i) {
    const int slot0 = wv * 256 + i * 64;
    const int c = slot0 >> 7;
    const int r = (slot0 & 127) + lane;
    glds16(gbase + (size_t)r * 512 + c * 8, lds + slot0 * 8);
  }
}
// Stage both operand tiles into one 32KB buffer (xs | ws halves).
__device__ __forceinline__ void stage_pair(const short* gx, const short* gw,
                                           short* buf, int wv, int lane) {
  stage_tile(gx, buf, wv, lane);
  stage_tile(gw, buf + 8192, wv, lane);
}

// ---------------- weight fp32 -> bf16 (regions contiguous in ws) ------------
__global__ __launch_bounds__(256) void k_convert(
    const float* __restrict__ w1, const float* __restrict__ wo1,
    const float* __restrict__ wo2, const float* __restrict__ wo3,
    short* __restrict__ dst) {
  int i = blockIdx.x * 256 + threadIdx.x;
  float v;
  if (i < 262144) v = w1[i];
  else if (i < 327680) v = wo1[i - 262144];
  else if (i < 335872) v = wo2[i - 327680];
  else if (i < 339968) v = wo3[i - 335872];
  else return;
  dst[i] = f2bf(v);
}

// ---------------- x[b][c][s] fp32  ->  xT[b][s][c] bf16 ---------------------
__global__ __launch_bounds__(256) void k_transpose(
    const float* __restrict__ x, short* __restrict__ xT) {
  __shared__ float tls[64][65];
  const int sb = blockIdx.x, cb = blockIdx.y, b = blockIdx.z;
  const int t = threadIdx.x;
  {
    const int cr = t >> 2, ss = (t & 3) * 16;
    const float* src = x + ((size_t)b * 512 + cb * 64 + cr) * S_TOT + sb * 64 + ss;
    f4_t v0 = *(const f4_t*)(src);
    f4_t v1 = *(const f4_t*)(src + 4);
    f4_t v2 = *(const f4_t*)(src + 8);
    f4_t v3 = *(const f4_t*)(src + 12);
#pragma unroll
    for (int j = 0; j < 4; ++j) {
      tls[cr][ss + j]      = v0[j];
      tls[cr][ss + 4 + j]  = v1[j];
      tls[cr][ss + 8 + j]  = v2[j];
      tls[cr][ss + 12 + j] = v3[j];
    }
  }
  __syncthreads();
  {
    const int sr = t >> 2, cs = (t & 3) * 16;
    alignas(16) short tmp[16];
#pragma unroll
    for (int j = 0; j < 16; ++j) tmp[j] = f2bf(tls[cs + j][sr]);
    short* dst = xT + ((size_t)b * S_TOT + sb * 64 + sr) * 512 + cb * 64 + cs;
    *(bf8_t*)dst       = *(const bf8_t*)&tmp[0];
    *(bf8_t*)(dst + 8) = *(const bf8_t*)&tmp[8];
  }
}

// ---------------- occ chain: 3 fused GEMMs per 128-voxel tile ---------------
__global__ __launch_bounds__(256) void k_occ(
    const short* __restrict__ xT, const short* __restrict__ wo1,
    const short* __restrict__ wo2, const short* __restrict__ wo3,
    const float* __restrict__ bo1, const float* __restrict__ bo2,
    short* __restrict__ occ, float* __restrict__ sumocc) {
  __shared__ short smem[32768];  // 64KB: buf0 | buf1 (32KB each)
  short* const buf0 = smem;
  short* const buf1 = smem + 16384;
  short* const h1s = buf0;   // 32KB planar [c4-chunk][s] after K-loop
  short* const h2s = buf1;   // 16KB planar [c8-chunk][s]
  const int tile = blockIdx.x, b = blockIdx.y;
  const int s0 = tile * 128;
  const int t = threadIdx.x, lane = t & 63, wv = t >> 6;
  const int q = lane >> 4, li = lane & 15;
  const int mh = (wv & 1) * 64, nh = (wv >> 1) * 64;
  const short* xTb = xT + ((size_t)b * S_TOT + s0) * 512;
  const f4_t fz = {0.f, 0.f, 0.f, 0.f};

  // phase 1: h1 = relu(Wo1 @ x + b1o)  [c4=128 x s=128], K=512, pipelined
  f4_t acc[4][4];
#pragma unroll
  for (int i = 0; i < 4; ++i)
#pragma unroll
    for (int j = 0; j < 4; ++j) acc[i][j] = fz;

  stage_pair(xTb, wo1, buf1, wv, lane);  // prologue k0=0 -> buf1
  int cur = 1;
  for (int i = 0; i < 8; ++i) {
    __syncthreads();  // drains glds for this step; protects buffer reuse
    if (i < 7)
      stage_pair(xTb + (i + 1) * 64, wo1 + (i + 1) * 64,
                 (cur ? buf0 : buf1), wv, lane);
    const short* xs = cur ? buf1 : buf0;
    const short* wsp = xs + 8192;
#pragma unroll
    for (int kk = 0; kk < 2; ++kk) {
      const int pl = (4 * kk + q) * 128;
      bf8_t a[4], bb[4];
#pragma unroll
      for (int ma = 0; ma < 4; ++ma)
        a[ma] = *(const bf8_t*)&wsp[(pl + mh + 16 * ma + li) * 8];
#pragma unroll
      for (int nb = 0; nb < 4; ++nb)
        bb[nb] = *(const bf8_t*)&xs[(pl + nh + 16 * nb + li) * 8];
#pragma unroll
      for (int ma = 0; ma < 4; ++ma)
#pragma unroll
        for (int nb = 0; nb < 4; ++nb)
          acc[ma][nb] = MFMA(a[ma], bb[nb], acc[ma][nb], 0, 0, 0);
    }
    cur ^= 1;
  }
  __syncthreads();
  // bias+relu -> h1s planar [c4-chunk][s]
#pragma unroll
  for (int ma = 0; ma < 4; ++ma) {
    const int c40 = mh + 16 * ma + 4 * q;
    f4_t bv = *(const f4_t*)(bo1 + c40);
#pragma unroll
    for (int nb = 0; nb < 4; ++nb) {
      const int sl = nh + 16 * nb + li;
      s4_t p;
#pragma unroll
      for (int r = 0; r < 4; ++r) p[r] = f2bf(fmaxf(acc[ma][nb][r] + bv[r], 0.0f));
      *(s4_t*)&h1s[((c40 >> 3) * 128 + sl) * 8 + (c40 & 7)] = p;
    }
  }
  __syncthreads();
  // phase 2: h2 = relu(Wo2 @ h1 + b2o)  [c8=64 x s=128], K=c4=128
  f4_t a2[4][2];
#pragma unroll
  for (int i = 0; i < 4; ++i) { a2[i][0] = fz; a2[i][1] = fz; }
#pragma unroll
  for (int kk = 0; kk < 4; ++kk) {
    const int pl = (4 * kk + q) * 128;
    bf8_t a[4], bb[2];
#pragma unroll
    for (int ma = 0; ma < 4; ++ma)
      a[ma] = *(const bf8_t*)(wo2 + (size_t)(16 * ma + li) * 128 + kk * 32 + q * 8);
#pragma unroll
    for (int nb = 0; nb < 2; ++nb)
      bb[nb] = *(const bf8_t*)&h1s[(pl + 32 * wv + 16 * nb + li) * 8];
#pragma unroll
    for (int ma = 0; ma < 4; ++ma)
#pragma unroll
      for (int nb = 0; nb < 2; ++nb)
        a2[ma][nb] = MFMA(a[ma], bb[nb], a2[ma][nb], 0, 0, 0);
  }
  // h2 -> h2s planar [c8-chunk][s]; wave-private s rows (no barrier)
#pragma unroll
  for (int ma = 0; ma < 4; ++ma) {
    const int c80 = 16 * ma + 4 * q;
    f4_t bv = *(const f4_t*)(bo2 + c80);
#pragma unroll
    for (int nb = 0; nb < 2; ++nb) {
      const int sl = 32 * wv + 16 * nb + li;
      s4_t p;
#pragma unroll
      for (int r = 0; r < 4; ++r) p[r] = f2bf(fmaxf(a2[ma][nb][r] + bv[r], 0.0f));
      *(s4_t*)&h2s[((c80 >> 3) * 128 + sl) * 8 + (c80 & 7)] = p;
    }
  }
  // phase 3: occ = |Wo3 @ h2|  [o=64 x s=128], K=c8=64
  f4_t a3[4][2];
#pragma unroll
  for (int i = 0; i < 4; ++i) { a3[i][0] = fz; a3[i][1] = fz; }
#pragma unroll
  for (int kk = 0; kk < 2; ++kk) {
    const int pl = (4 * kk + q) * 128;
    bf8_t a[4], bb[2];
#pragma unroll
    for (int ma = 0; ma < 4; ++ma)
      a[ma] = *(const bf8_t*)(wo3 + (size_t)(16 * ma + li) * 64 + kk * 32 + q * 8);
#pragma unroll
    for (int nb = 0; nb < 2; ++nb)
      bb[nb] = *(const bf8_t*)&h2s[(pl + 32 * wv + 16 * nb + li) * 8];
#pragma unroll
    for (int ma = 0; ma < 4; ++ma)
#pragma unroll
      for (int nb = 0; nb < 2; ++nb)
        a3[ma][nb] = MFMA(a[ma], bb[nb], a3[ma][nb], 0, 0, 0);
  }
#pragma unroll
  for (int ma = 0; ma < 4; ++ma)
#pragma unroll
    for (int nb = 0; nb < 2; ++nb) {
      const int o = 16 * ma + 4 * q;
      const int sgl = s0 + 32 * wv + 16 * nb + li;
#pragma unroll
      for (int r = 0; r < 4; ++r)
        occ[((size_t)(b * 64 + o + r)) * S_TOT + sgl] = f2bf(fabsf(a3[ma][nb][r]));
    }
  // sumocc[b][o] += sum_s |occ| (fp32); reduce over li (16-lane groups), then
  // atomics cover (wv, q) spread. 16 atomics per li==0 lane.
#pragma unroll
  for (int ma = 0; ma < 4; ++ma)
#pragma unroll
    for (int r = 0; r < 4; ++r) {
      float v = fabsf(a3[ma][0][r]) + fabsf(a3[ma][1][r]);
#pragma unroll
      for (int m = 1; m < 16; m <<= 1) v += __shfl_xor(v, m, 64);
      if (li == 0) atomicAdd(&sumocc[b * 64 + 16 * ma + 4 * q + r], v);
    }
}

// ---------------- r1 GEMM + spatial contraction into M ----------------------
// block: (sg, cb, b); 4 s-tiles of 128; j-tile = 128 (cb); K = 512; pipelined
__global__ __launch_bounds__(256) void k_feat(
    const short* __restrict__ xT, const short* __restrict__ w1,
    const float* __restrict__ b1, const short* __restrict__ occ,
    float* __restrict__ M) {
  __shared__ short smem[32768];  // 64KB: buf0 | buf1
  short* const buf0 = smem;
  short* const buf1 = smem + 16384;
  short* const r1s = buf0;  // 32KB planar [s-chunk][j] after each K-loop
  const int sg = blockIdx.x, cb = blockIdx.y, b = blockIdx.z;
  const int t = threadIdx.x, lane = t & 63, wv = t >> 6;
  const int q = lane >> 4, li = lane & 15;
  const int mh = (wv & 1) * 64, nh = (wv >> 1) * 64;
  const short* w1b = w1 + (size_t)(cb * 128) * 512;
  const f4_t fz = {0.f, 0.f, 0.f, 0.f};

  float biasv[4];
#pragma unroll
  for (int nb = 0; nb < 4; ++nb) biasv[nb] = b1[cb * 128 + nh + 16 * nb + li];

  f4_t macc[4][2];
#pragma unroll
  for (int i = 0; i < 4; ++i) { macc[i][0] = fz; macc[i][1] = fz; }

  // prologue: tile0 k0=0 -> buf1 (later tiles' prologues overlap M-contraction)
  stage_pair(xT + ((size_t)b * S_TOT + sg * 512) * 512, w1b, buf1, wv, lane);

  for (int tt = 0; tt < 4; ++tt) {
    const int s_t = sg * 512 + tt * 128;
    const short* xTt = xT + ((size_t)b * S_TOT + s_t) * 512;
    f4_t acc[4][4];
#pragma unroll
    for (int i = 0; i < 4; ++i)
#pragma unroll
      for (int j = 0; j < 4; ++j) acc[i][j] = fz;

    int cur = 1;
    for (int i = 0; i < 8; ++i) {
      __syncthreads();  // drains glds for this step; protects buffer reuse
      if (i < 7)
        stage_pair(xTt + (i + 1) * 64, w1b + (i + 1) * 64,
                   (cur ? buf0 : buf1), wv, lane);
      const short* xs = cur ? buf1 : buf0;
      const short* wsp = xs + 8192;
#pragma unroll
      for (int kk = 0; kk < 2; ++kk) {
        const int pl = (4 * kk + q) * 128;
        bf8_t a[4], bb[4];
#pragma unroll
        for (int ma = 0; ma < 4; ++ma)
          a[ma] = *(const bf8_t*)&xs[(pl + mh + 16 * ma + li) * 8];
#pragma unroll
        for (int nb = 0; nb < 4; ++nb)
          bb[nb] = *(const bf8_t*)&wsp[(pl + nh + 16 * nb + li) * 8];
#pragma unroll
        for (int ma = 0; ma < 4; ++ma)
#pragma unroll
          for (int nb = 0; nb < 4; ++nb)
            acc[ma][nb] = MFMA(a[ma], bb[nb], acc[ma][nb], 0, 0, 0);
      }
      cur ^= 1;
    }
    __syncthreads();  // all buf reads done; nothing in flight
    // r1 = relu(acc + b1) -> r1s planar [s-chunk][j] (buf0 region)
#pragma unroll
    for (int ma = 0; ma < 4; ++ma) {
      const int sl0 = mh + 16 * ma + 4 * q;  // 4 consecutive s
#pragma unroll
      for (int nb = 0; nb < 4; ++nb) {
        const int jl = nh + 16 * nb + li;
        s4_t p;
#pragma unroll
        for (int r = 0; r < 4; ++r)
          p[r] = f2bf(fmaxf(acc[ma][nb][r] + biasv[nb], 0.0f));
        *(s4_t*)&r1s[((sl0 >> 3) * 128 + jl) * 8 + (sl0 & 7)] = p;
      }
    }
    __syncthreads();  // r1s visible
    // next tile's prologue + occ prefetch fly during the M-contraction
    if (tt < 3)
      stage_pair(xTt + (size_t)128 * 512, w1b, buf1, wv, lane);
    const short* ob = occ + (size_t)b * 64 * S_TOT + s_t;
    bf8_t af[4][4];
#pragma unroll
    for (int kc = 0; kc < 4; ++kc)
#pragma unroll
      for (int ma = 0; ma < 4; ++ma)
        af[ma][kc] = *(const bf8_t*)(ob + (size_t)(16 * ma + li) * S_TOT +
                                     kc * 32 + q * 8);
    // M[o][j] += occ[o][s] * r1[j][s]  (K = s = 128)
#pragma unroll
    for (int kc = 0; kc < 4; ++kc) {
      const int pl = (4 * kc + q) * 128;
      bf8_t bb[2];
#pragma unroll
      for (int nb = 0; nb < 2; ++nb)
        bb[nb] = *(const bf8_t*)&r1s[(pl + 32 * wv + 16 * nb + li) * 8];
#pragma unroll
      for (int ma = 0; ma < 4; ++ma)
#pragma unroll
        for (int nb = 0; nb < 2; ++nb)
          macc[ma][nb] = MFMA(af[ma][kc], bb[nb], macc[ma][nb], 0, 0, 0);
    }
  }
  // flush partial M (64 x 128 per block) once
#pragma unroll
  for (int ma = 0; ma < 4; ++ma)
#pragma unroll
    for (int nb = 0; nb < 2; ++nb) {
      const int jg = cb * 128 + 32 * wv + 16 * nb + li;
#pragma unroll
      for (int r = 0; r < 4; ++r) {
        const int o = 16 * ma + 4 * q + r;
        atomicAdd(&M[((size_t)b * 64 + o) * 512 + jg], macc[ma][nb][r]);
      }
    }
}

// ---------------- epilogue: out = (M @ W2^T + sumocc * b2^T) / S ------------
// grid (32 cg, 4 og, 4 b); thread (o = og*16 + t>>4, c = cg*16 + t&15)
__global__ __launch_bounds__(256) void k_out(
    const float* __restrict__ M, const float* __restrict__ sumocc,
    const float* __restrict__ w2, const float* __restrict__ b2,
    float* __restrict__ out) {
  const int cg = blockIdx.x, og = blockIdx.y, b = blockIdx.z;
  const int t = threadIdx.x;
  const int o = og * 16 + (t >> 4);
  const int c = cg * 16 + (t & 15);
  const float* mr = M + ((size_t)b * 64 + o) * 512;
  const float* wr = w2 + (size_t)c * 512;
  float a = 0.0f;
  for (int j = 0; j < 512; j += 4) {
    f4_t mv = *(const f4_t*)(mr + j);
    f4_t wv = *(const f4_t*)(wr + j);
    a += mv[0] * wv[0] + mv[1] * wv[1] + mv[2] * wv[2] + mv[3] * wv[3];
  }
  out[((size_t)b * 64 + o) * 512 + c] =
      (a + sumocc[b * 64 + o] * b2[c]) * (1.0f / 16384.0f);
}

// ---------------- launch ----------------------------------------------------
// ws layout (bytes):
//   0         xT      4*16384*512 bf16 = 67108864
//   67108864  wb      339968 bf16 (w_add1 | w_occ1 | w_occ2 | w_occ3) = 679936
//   67788800  occ     4*64*16384 bf16  = 8388608
//   76177408  M       4*64*512 fp32    = 524288
//   76701696  sumocc  256 fp32         = 1024
extern "C" void kernel_launch(void* const* d_in, const int* in_sizes, int n_in,
                              void* d_out, int out_size, void* d_ws, size_t ws_size,
                              hipStream_t stream) {
  (void)in_sizes; (void)n_in; (void)out_size; (void)ws_size;
  const float* x      = (const float*)d_in[0];
  const float* w_add1 = (const float*)d_in[1];
  const float* b_add1 = (const float*)d_in[2];
  const float* w_add2 = (const float*)d_in[3];
  const float* b_add2 = (const float*)d_in[4];
  const float* w_occ1 = (const float*)d_in[5];
  const float* b_occ1 = (const float*)d_in[6];
  const float* w_occ2 = (const float*)d_in[7];
  const float* b_occ2 = (const float*)d_in[8];
  const float* w_occ3 = (const float*)d_in[9];

  char* ws = (char*)d_ws;
  short* xT      = (short*)(ws);
  short* wb      = (short*)(ws + 67108864);
  short* occ     = (short*)(ws + 67788800);
  float* M       = (float*)(ws + 76177408);
  float* sumocc  = (float*)(ws + 76701696);

  hipMemsetAsync(M, 0, 524288 + 1024, stream);  // M + sumocc
  k_convert<<<dim3(1328), dim3(256), 0, stream>>>(w_add1, w_occ1, w_occ2, w_occ3, wb);
  k_transpose<<<dim3(256, 8, 4), dim3(256), 0, stream>>>(x, xT);

  const short* wb1  = wb;
  const short* wbo1 = wb + 262144;
  const short* wbo2 = wb + 327680;
  const short* wbo3 = wb + 335872;
  k_occ<<<dim3(128, 4), dim3(256), 0, stream>>>(xT, wbo1, wbo2, wbo3,
                                                b_occ1, b_occ2, occ, sumocc);
  k_feat<<<dim3(32, 4, 4), dim3(256), 0, stream>>>(xT, wb1, b_add1, occ, M);
  k_out<<<dim3(32, 4, 4), dim3(256), 0, stream>>>(M, sumocc, w_add2, b_add2,
                                                  (float*)d_out);
}

// Round 4
// 403.424 us; speedup vs baseline: 1.1132x; 1.1132x over previous
//
#include <hip/hip_runtime.h>

// OccurrencePool restructured:
//   r1  = relu(W1 x + b1)                          (bf16 MFMA, 34.4 GF)
//   occ = |W3 relu(W2o relu(W1o x + b1o) + b2o)|   (bf16 MFMA, 10.2 GF)
//   M[b,o,j]   = sum_s occ[b,o,s] r1[b,j,s]        (bf16 MFMA, 4.3 GF)
//   out[b,o,c] = (sum_j M[o,j] W2[c,j] + b2[c]*sumocc[b,o]) / S
// R4: pre-swizzled GLOBAL layouts = planar LDS image, so every glds staging
// instruction is lane-contiguous (1KB/inst). R3's staging had 1KB lane stride
// (64 lines per instruction) — the entire latency disaster.
// Tile layout (per 128-voxel tile, per 64-wide K chunk kc):
//   linear = kc*8192 + k8*1024 + row*8 + k0   (shorts; k8=(k>>3)&7, k0=k&7)

#define S_TOT 16384  // T*H*W per batch

typedef __attribute__((ext_vector_type(8))) short bf8_t;  // 8 bf16 (4 VGPRs)
typedef __attribute__((ext_vector_type(4))) short s4_t;   // 4 bf16
typedef __attribute__((ext_vector_type(4))) float f4_t;

#define MFMA __builtin_amdgcn_mfma_f32_16x16x32_bf16

__device__ __forceinline__ short f2bf(float f) {
  union { float f; unsigned u; } v; v.f = f;
  unsigned u = v.u + 0x7FFFu + ((v.u >> 16) & 1u);  // RNE
  return (short)(u >> 16);
}

__device__ __forceinline__ void glds16(const void* g, void* l) {
  __builtin_amdgcn_global_load_lds(
      (const __attribute__((address_space(1))) void*)g,
      (__attribute__((address_space(3))) void*)l, 16, 0, 0);
}

// Contiguous 16KB global -> LDS copy (layouts identical). 4 glds/wave, each
// lane-contiguous 1KB: g + off + lane*8 shorts; HW adds lane*16B on LDS side.
__device__ __forceinline__ void stage16k(const short* g, short* lds,
                                         int wv, int lane) {
#pragma unroll
  for (int i = 0; i < 4; ++i) {
    const int off = (wv * 4 + i) * 512;
    glds16(g + off + lane * 8, lds + off);
  }
}

// ---------------- weights fp32 -> bf16, w1/wo1 pre-swizzled -----------------
__global__ __launch_bounds__(256) void k_convert(
    const float* __restrict__ w1, const float* __restrict__ wo1,
    const float* __restrict__ wo2, const float* __restrict__ wo3,
    short* __restrict__ dst) {
  int i = blockIdx.x * 256 + threadIdx.x;
  if (i < 262144) {  // w1[j][k] -> [jc][kc][k8][j&127][k0]
    const int j = i >> 9, k = i & 511;
    const int di = ((j >> 7) * 8 + (k >> 6)) * 8192 + ((k >> 3) & 7) * 1024 +
                   (j & 127) * 8 + (k & 7);
    dst[di] = f2bf(w1[i]);
  } else if (i < 327680) {  // wo1[c4][k] -> [kc][k8][c4][k0]
    const int e = i - 262144;
    const int c4 = e >> 9, k = e & 511;
    const int di = 262144 + (k >> 6) * 8192 + ((k >> 3) & 7) * 1024 +
                   c4 * 8 + (k & 7);
    dst[di] = f2bf(wo1[e]);
  } else if (i < 335872) {
    dst[i] = f2bf(wo2[i - 327680]);
  } else if (i < 339968) {
    dst[i] = f2bf(wo3[i - 335872]);
  }
}

// ------ x[b][c][s] fp32 -> xTs[b][st][kc][k8][s(128)][k0] bf16 --------------
__global__ __launch_bounds__(256) void k_transpose(
    const float* __restrict__ x, short* __restrict__ xTs) {
  __shared__ float tls[64][65];
  const int sb = blockIdx.x, cb = blockIdx.y, b = blockIdx.z;
  const int t = threadIdx.x;
  {
    const int cr = t >> 2, ss = (t & 3) * 16;
    const float* src = x + ((size_t)b * 512 + cb * 64 + cr) * S_TOT + sb * 64 + ss;
    f4_t v0 = *(const f4_t*)(src);
    f4_t v1 = *(const f4_t*)(src + 4);
    f4_t v2 = *(const f4_t*)(src + 8);
    f4_t v3 = *(const f4_t*)(src + 12);
#pragma unroll
    for (int j = 0; j < 4; ++j) {
      tls[cr][ss + j]      = v0[j];
      tls[cr][ss + 4 + j]  = v1[j];
      tls[cr][ss + 8 + j]  = v2[j];
      tls[cr][ss + 12 + j] = v3[j];
    }
  }
  __syncthreads();
  {
    const int sr = t >> 2, cs = (t & 3) * 16;  // k window cs..cs+15 (2 chunks)
    alignas(16) short tmp[16];
#pragma unroll
    for (int j = 0; j < 16; ++j) tmp[j] = f2bf(tls[cs + j][sr]);
    const int st = sb >> 1, s_in = (sb & 1) * 64 + sr, k8 = cs >> 3;
    short* base = xTs + (((size_t)(b * 128 + st) * 8 + cb) * 8 + k8) * 1024 +
                  s_in * 8;
    *(bf8_t*)base          = *(const bf8_t*)&tmp[0];
    *(bf8_t*)(base + 1024) = *(const bf8_t*)&tmp[8];
  }
}

// ---------------- occ chain: 3 fused GEMMs per 128-voxel tile ---------------
// occP output layout per tile: [s8(16)][o(64)][s0(8)] = planar A-operand image
__global__ __launch_bounds__(256) void k_occ(
    const short* __restrict__ xTs, const short* __restrict__ wo1,
    const short* __restrict__ wo2, const short* __restrict__ wo3,
    const float* __restrict__ bo1, const float* __restrict__ bo2,
    short* __restrict__ occP, float* __restrict__ sumocc) {
  __shared__ short smem[32768];  // 64KB: buf0 | buf1 (32KB each)
  short* const buf0 = smem;
  short* const buf1 = smem + 16384;
  short* const h1s = buf0;   // 32KB planar [c4chunk][s] after K-loop
  short* const h2s = buf1;   // 16KB planar [c8chunk][s]
  const int tile = blockIdx.x, b = blockIdx.y;
  const int t = threadIdx.x, lane = t & 63, wv = t >> 6;
  const int q = lane >> 4, li = lane & 15;
  const int mh = (wv & 1) * 64, nh = (wv >> 1) * 64;
  const short* xTb = xTs + (size_t)(b * 128 + tile) * 65536;
  const f4_t fz = {0.f, 0.f, 0.f, 0.f};

  // phase 1: h1 = relu(Wo1 @ x + b1o)  [c4=128 x s=128], K=512, pipelined
  f4_t acc[4][4];
#pragma unroll
  for (int i = 0; i < 4; ++i)
#pragma unroll
    for (int j = 0; j < 4; ++j) acc[i][j] = fz;

  stage16k(xTb, buf1, wv, lane);          // kc=0 -> buf1
  stage16k(wo1, buf1 + 8192, wv, lane);
  int cur = 1;
  for (int i = 0; i < 8; ++i) {
    __syncthreads();
    if (i < 7) {
      short* nb_ = cur ? buf0 : buf1;
      stage16k(xTb + (i + 1) * 8192, nb_, wv, lane);
      stage16k(wo1 + (i + 1) * 8192, nb_ + 8192, wv, lane);
    }
    const short* xs = cur ? buf1 : buf0;
    const short* wsp = xs + 8192;
#pragma unroll
    for (int kk = 0; kk < 2; ++kk) {
      const int pl = (4 * kk + q) * 128;
      bf8_t a[4], bb[4];
#pragma unroll
      for (int ma = 0; ma < 4; ++ma)
        a[ma] = *(const bf8_t*)&wsp[(pl + mh + 16 * ma + li) * 8];
#pragma unroll
      for (int nb = 0; nb < 4; ++nb)
        bb[nb] = *(const bf8_t*)&xs[(pl + nh + 16 * nb + li) * 8];
#pragma unroll
      for (int ma = 0; ma < 4; ++ma)
#pragma unroll
        for (int nb = 0; nb < 4; ++nb)
          acc[ma][nb] = MFMA(a[ma], bb[nb], acc[ma][nb], 0, 0, 0);
    }
    cur ^= 1;
  }
  __syncthreads();
  // bias+relu -> h1s planar [c4chunk][s]
#pragma unroll
  for (int ma = 0; ma < 4; ++ma) {
    const int c40 = mh + 16 * ma + 4 * q;
    f4_t bv = *(const f4_t*)(bo1 + c40);
#pragma unroll
    for (int nb = 0; nb < 4; ++nb) {
      const int sl = nh + 16 * nb + li;
      s4_t p;
#pragma unroll
      for (int r = 0; r < 4; ++r) p[r] = f2bf(fmaxf(acc[ma][nb][r] + bv[r], 0.0f));
      *(s4_t*)&h1s[((c40 >> 3) * 128 + sl) * 8 + (c40 & 7)] = p;
    }
  }
  __syncthreads();
  // phase 2: h2 = relu(Wo2 @ h1 + b2o)  [c8=64 x s=128], K=c4=128
  f4_t a2[4][2];
#pragma unroll
  for (int i = 0; i < 4; ++i) { a2[i][0] = fz; a2[i][1] = fz; }
#pragma unroll
  for (int kk = 0; kk < 4; ++kk) {
    const int pl = (4 * kk + q) * 128;
    bf8_t a[4], bb[2];
#pragma unroll
    for (int ma = 0; ma < 4; ++ma)
      a[ma] = *(const bf8_t*)(wo2 + (size_t)(16 * ma + li) * 128 + kk * 32 + q * 8);
#pragma unroll
    for (int nb = 0; nb < 2; ++nb)
      bb[nb] = *(const bf8_t*)&h1s[(pl + 32 * wv + 16 * nb + li) * 8];
#pragma unroll
    for (int ma = 0; ma < 4; ++ma)
#pragma unroll
      for (int nb = 0; nb < 2; ++nb)
        a2[ma][nb] = MFMA(a[ma], bb[nb], a2[ma][nb], 0, 0, 0);
  }
  // h2 -> h2s planar [c8chunk][s]; wave-private s rows (no barrier)
#pragma unroll
  for (int ma = 0; ma < 4; ++ma) {
    const int c80 = 16 * ma + 4 * q;
    f4_t bv = *(const f4_t*)(bo2 + c80);
#pragma unroll
    for (int nb = 0; nb < 2; ++nb) {
      const int sl = 32 * wv + 16 * nb + li;
      s4_t p;
#pragma unroll
      for (int r = 0; r < 4; ++r) p[r] = f2bf(fmaxf(a2[ma][nb][r] + bv[r], 0.0f));
      *(s4_t*)&h2s[((c80 >> 3) * 128 + sl) * 8 + (c80 & 7)] = p;
    }
  }
  // phase 3: occ = |Wo3 @ h2|  [o=64 x s=128], K=c8=64
  f4_t a3[4][2];
#pragma unroll
  for (int i = 0; i < 4; ++i) { a3[i][0] = fz; a3[i][1] = fz; }
#pragma unroll
  for (int kk = 0; kk < 2; ++kk) {
    const int pl = (4 * kk + q) * 128;
    bf8_t a[4], bb[2];
#pragma unroll
    for (int ma = 0; ma < 4; ++ma)
      a[ma] = *(const bf8_t*)(wo3 + (size_t)(16 * ma + li) * 64 + kk * 32 + q * 8);
#pragma unroll
    for (int nb = 0; nb < 2; ++nb)
      bb[nb] = *(const bf8_t*)&h2s[(pl + 32 * wv + 16 * nb + li) * 8];
#pragma unroll
    for (int ma = 0; ma < 4; ++ma)
#pragma unroll
      for (int nb = 0; nb < 2; ++nb)
        a3[ma][nb] = MFMA(a[ma], bb[nb], a3[ma][nb], 0, 0, 0);
  }
  // |.| -> occP planar tile [s8][o][s0]
  short* ot = occP + (size_t)(b * 128 + tile) * 8192;
#pragma unroll
  for (int ma = 0; ma < 4; ++ma)
#pragma unroll
    for (int nb = 0; nb < 2; ++nb) {
      const int o = 16 * ma + 4 * q;
      const int sl = 32 * wv + 16 * nb + li;
#pragma unroll
      for (int r = 0; r < 4; ++r)
        ot[(sl >> 3) * 512 + (o + r) * 8 + (sl & 7)] = f2bf(fabsf(a3[ma][nb][r]));
    }
  // sumocc[b][o] += sum_s |occ| (fp32)
#pragma unroll
  for (int ma = 0; ma < 4; ++ma)
#pragma unroll
    for (int r = 0; r < 4; ++r) {
      float v = fabsf(a3[ma][0][r]) + fabsf(a3[ma][1][r]);
#pragma unroll
      for (int m = 1; m < 16; m <<= 1) v += __shfl_xor(v, m, 64);
      if (li == 0) atomicAdd(&sumocc[b * 64 + 16 * ma + 4 * q + r], v);
    }
}

// ---------------- r1 GEMM + spatial contraction into M ----------------------
__global__ __launch_bounds__(256) void k_feat(
    const short* __restrict__ xTs, const short* __restrict__ w1s,
    const float* __restrict__ b1, const short* __restrict__ occP,
    float* __restrict__ M) {
  __shared__ short smem[32768];  // 64KB: buf0 | buf1
  short* const buf0 = smem;
  short* const buf1 = smem + 16384;
  short* const r1s = buf0;  // 32KB planar [schunk][j] after each K-loop
  const int sg = blockIdx.x, cb = blockIdx.y, b = blockIdx.z;
  const int t = threadIdx.x, lane = t & 63, wv = t >> 6;
  const int q = lane >> 4, li = lane & 15;
  const int mh = (wv & 1) * 64, nh = (wv >> 1) * 64;
  const short* w1b = w1s + (size_t)cb * 65536;  // [kc][k8][j][k0] for this jc
  const f4_t fz = {0.f, 0.f, 0.f, 0.f};

  float biasv[4];
#pragma unroll
  for (int nb = 0; nb < 4; ++nb) biasv[nb] = b1[cb * 128 + nh + 16 * nb + li];

  f4_t macc[4][2];
#pragma unroll
  for (int i = 0; i < 4; ++i) { macc[i][0] = fz; macc[i][1] = fz; }

  // prologue: tile0 kc=0 -> buf1
  {
    const short* xT0 = xTs + (size_t)(b * 128 + sg * 4) * 65536;
    stage16k(xT0, buf1, wv, lane);
    stage16k(w1b, buf1 + 8192, wv, lane);
  }

  for (int tt = 0; tt < 4; ++tt) {
    const int st = sg * 4 + tt;
    const short* xTb = xTs + (size_t)(b * 128 + st) * 65536;
    f4_t acc[4][4];
#pragma unroll
    for (int i = 0; i < 4; ++i)
#pragma unroll
      for (int j = 0; j < 4; ++j) acc[i][j] = fz;

    int cur = 1;
    for (int i = 0; i < 8; ++i) {
      __syncthreads();
      if (i < 7) {
        short* nb_ = cur ? buf0 : buf1;
        stage16k(xTb + (i + 1) * 8192, nb_, wv, lane);
        stage16k(w1b + (i + 1) * 8192, nb_ + 8192, wv, lane);
      }
      const short* xs = cur ? buf1 : buf0;
      const short* wsp = xs + 8192;
#pragma unroll
      for (int kk = 0; kk < 2; ++kk) {
        const int pl = (4 * kk + q) * 128;
        bf8_t a[4], bb[4];
#pragma unroll
        for (int ma = 0; ma < 4; ++ma)
          a[ma] = *(const bf8_t*)&xs[(pl + mh + 16 * ma + li) * 8];
#pragma unroll
        for (int nb = 0; nb < 4; ++nb)
          bb[nb] = *(const bf8_t*)&wsp[(pl + nh + 16 * nb + li) * 8];
#pragma unroll
        for (int ma = 0; ma < 4; ++ma)
#pragma unroll
          for (int nb = 0; nb < 4; ++nb)
            acc[ma][nb] = MFMA(a[ma], bb[nb], acc[ma][nb], 0, 0, 0);
      }
      cur ^= 1;
    }
    __syncthreads();  // all buf reads done
    // r1 = relu(acc + b1) -> r1s planar [schunk][j] (buf0)
#pragma unroll
    for (int ma = 0; ma < 4; ++ma) {
      const int sl0 = mh + 16 * ma + 4 * q;  // 4 consecutive s
#pragma unroll
      for (int nb = 0; nb < 4; ++nb) {
        const int jl = nh + 16 * nb + li;
        s4_t p;
#pragma unroll
        for (int r = 0; r < 4; ++r)
          p[r] = f2bf(fmaxf(acc[ma][nb][r] + biasv[nb], 0.0f));
        *(s4_t*)&r1s[((sl0 >> 3) * 128 + jl) * 8 + (sl0 & 7)] = p;
      }
    }
    __syncthreads();  // r1s visible
    // next tile's prologue (buf1 idle: last read at i==6) + occ prefetch
    if (tt < 3) {
      stage16k(xTb + 65536, buf1, wv, lane);
      stage16k(w1b, buf1 + 8192, wv, lane);
    }
    const short* ot = occP + (size_t)(b * 128 + st) * 8192;
    bf8_t af[4][4];
#pragma unroll
    for (int kc = 0; kc < 4; ++kc)
#pragma unroll
      for (int ma = 0; ma < 4; ++ma)  // planar: 16 lanes read 256B contiguous
        af[ma][kc] = *(const bf8_t*)(ot + ((kc * 4 + q) * 64 + 16 * ma + li) * 8);
    // M[o][j] += occ[o][s] * r1[j][s]  (K = s = 128)
#pragma unroll
    for (int kc = 0; kc < 4; ++kc) {
      const int pl = (4 * kc + q) * 128;
      bf8_t bb[2];
#pragma unroll
      for (int nb = 0; nb < 2; ++nb)
        bb[nb] = *(const bf8_t*)&r1s[(pl + 32 * wv + 16 * nb + li) * 8];
#pragma unroll
      for (int ma = 0; ma < 4; ++ma)
#pragma unroll
        for (int nb = 0; nb < 2; ++nb)
          macc[ma][nb] = MFMA(af[ma][kc], bb[nb], macc[ma][nb], 0, 0, 0);
    }
  }
  // flush partial M (64 x 128 per block) once
#pragma unroll
  for (int ma = 0; ma < 4; ++ma)
#pragma unroll
    for (int nb = 0; nb < 2; ++nb) {
      const int jg = cb * 128 + 32 * wv + 16 * nb + li;
#pragma unroll
      for (int r = 0; r < 4; ++r) {
        const int o = 16 * ma + 4 * q + r;
        atomicAdd(&M[((size_t)b * 64 + o) * 512 + jg], macc[ma][nb][r]);
      }
    }
}

// ---------------- epilogue: out = (M @ W2^T + sumocc * b2^T) / S ------------
__global__ __launch_bounds__(256) void k_out(
    const float* __restrict__ M, const float* __restrict__ sumocc,
    const float* __restrict__ w2, const float* __restrict__ b2,
    float* __restrict__ out) {
  const int cg = blockIdx.x, og = blockIdx.y, b = blockIdx.z;
  const int t = threadIdx.x;
  const int o = og * 16 + (t >> 4);
  const int c = cg * 16 + (t & 15);
  const float* mr = M + ((size_t)b * 64 + o) * 512;
  const float* wr = w2 + (size_t)c * 512;
  float a = 0.0f;
  for (int j = 0; j < 512; j += 4) {
    f4_t mv = *(const f4_t*)(mr + j);
    f4_t wv = *(const f4_t*)(wr + j);
    a += mv[0] * wv[0] + mv[1] * wv[1] + mv[2] * wv[2] + mv[3] * wv[3];
  }
  out[((size_t)b * 64 + o) * 512 + c] =
      (a + sumocc[b * 64 + o] * b2[c]) * (1.0f / 16384.0f);
}

// ---------------- launch ----------------------------------------------------
// ws layout (bytes):
//   0         xTs     4*16384*512 bf16 = 67108864   (swizzled tiles)
//   67108864  wb      339968 bf16 (w1s | wo1s | wo2 | wo3) = 679936
//   67788800  occP    4*64*16384 bf16  = 8388608    (planar tiles)
//   76177408  M       4*64*512 fp32    = 524288
//   76701696  sumocc  256 fp32         = 1024
extern "C" void kernel_launch(void* const* d_in, const int* in_sizes, int n_in,
                              void* d_out, int out_size, void* d_ws, size_t ws_size,
                              hipStream_t stream) {
  (void)in_sizes; (void)n_in; (void)out_size; (void)ws_size;
  const float* x      = (const float*)d_in[0];
  const float* w_add1 = (const float*)d_in[1];
  const float* b_add1 = (const float*)d_in[2];
  const float* w_add2 = (const float*)d_in[3];
  const float* b_add2 = (const float*)d_in[4];
  const float* w_occ1 = (const float*)d_in[5];
  const float* b_occ1 = (const float*)d_in[6];
  const float* w_occ2 = (const float*)d_in[7];
  const float* b_occ2 = (const float*)d_in[8];
  const float* w_occ3 = (const float*)d_in[9];

  char* ws = (char*)d_ws;
  short* xTs     = (short*)(ws);
  short* wb      = (short*)(ws + 67108864);
  short* occP    = (short*)(ws + 67788800);
  float* M       = (float*)(ws + 76177408);
  float* sumocc  = (float*)(ws + 76701696);

  hipMemsetAsync(M, 0, 524288 + 1024, stream);  // M + sumocc
  k_convert<<<dim3(1328), dim3(256), 0, stream>>>(w_add1, w_occ1, w_occ2, w_occ3, wb);
  k_transpose<<<dim3(256, 8, 4), dim3(256), 0, stream>>>(x, xTs);

  const short* w1sp = wb;
  const short* wbo1 = wb + 262144;
  const short* wbo2 = wb + 327680;
  const short* wbo3 = wb + 335872;
  k_occ<<<dim3(128, 4), dim3(256), 0, stream>>>(xTs, wbo1, wbo2, wbo3,
                                                b_occ1, b_occ2, occP, sumocc);
  k_feat<<<dim3(32, 4, 4), dim3(256), 0, stream>>>(xTs, w1sp, b_add1, occP, M);
  k_out<<<dim3(32, 4, 4), dim3(256), 0, stream>>>(M, sumocc, w_add2, b_add2,
                                                  (float*)d_out);
}